// Round 1
// baseline (213.815 us; speedup 1.0000x reference)
//
#include <hip/hip_runtime.h>

#define OUT 7
#define SR 2
#define NCH 256
#define NB 2
#define NPER 256
#define NROI (NB * NPER)

struct RoiMeta {
    int   level;   // 0..3
    int   bidx;    // batch index
    float x1, y1;
    float bin_w, bin_h;
};

__global__ void roi_meta_kernel(const float* __restrict__ boxes,
                                RoiMeta* __restrict__ meta) {
    int r = blockIdx.x * blockDim.x + threadIdx.x;
    if (r >= NROI) return;
    float bx1 = boxes[r * 4 + 0];
    float by1 = boxes[r * 4 + 1];
    float bx2 = boxes[r * 4 + 2];
    float by2 = boxes[r * 4 + 3];

    // LevelMapper: floor(4 + log2(sqrt(area)/224 + 1e-6)), clip [2,5], -2
    float area = (bx2 - bx1) * (by2 - by1);
    float s    = sqrtf(area);
    float lvl  = floorf(4.0f + log2f(s / 224.0f + 1e-6f));
    lvl        = fminf(fmaxf(lvl, 2.0f), 5.0f);
    int level  = (int)lvl - 2;

    float scale = 0.25f / (float)(1 << level);   // 0.25,0.125,0.0625,0.03125
    float x1 = bx1 * scale;
    float y1 = by1 * scale;
    float x2 = bx2 * scale;
    float y2 = by2 * scale;
    float roi_w = fmaxf(x2 - x1, 1.0f);
    float roi_h = fmaxf(y2 - y1, 1.0f);

    RoiMeta m;
    m.level = level;
    m.bidx  = r / NPER;
    m.x1    = x1;
    m.y1    = y1;
    m.bin_w = roi_w * (1.0f / OUT);
    m.bin_h = roi_h * (1.0f / OUT);
    meta[r] = m;
}

__device__ __forceinline__ float bilinear_legacy(const float* __restrict__ plane,
                                                 int H, int W, float y, float x) {
    bool valid = (y >= -1.0f) && (y <= (float)H) && (x >= -1.0f) && (x <= (float)W);
    y = fmaxf(y, 0.0f);
    x = fmaxf(x, 0.0f);
    int yl = (int)y;
    int xl = (int)x;
    int yh, xh;
    if (yl >= H - 1) { yl = H - 1; yh = H - 1; y = (float)yl; }
    else             { yh = yl + 1; }
    if (xl >= W - 1) { xl = W - 1; xh = W - 1; x = (float)xl; }
    else             { xh = xl + 1; }
    float ly = y - (float)yl;
    float lx = x - (float)xl;
    float hy = 1.0f - ly;
    float hx = 1.0f - lx;
    const float* rowl = plane + (size_t)yl * W;
    const float* rowh = plane + (size_t)yh * W;
    float v = hy * hx * rowl[xl] + hy * lx * rowl[xh]
            + ly * hx * rowh[xl] + ly * lx * rowh[xh];
    return valid ? v : 0.0f;
}

__global__ void roi_align_kernel(const float* __restrict__ f0,
                                 const float* __restrict__ f1,
                                 const float* __restrict__ f2,
                                 const float* __restrict__ f3,
                                 const RoiMeta* __restrict__ meta,
                                 float* __restrict__ out) {
    int idx = blockIdx.x * blockDim.x + threadIdx.x;
    // idx = ((r*NCH + c)*OUT + ph)*OUT + pw ; 49*256 = 12544 = 196 waves -> wave-uniform r
    int pw = idx % OUT;
    int t  = idx / OUT;
    int ph = t % OUT;
    t /= OUT;
    int c = t % NCH;
    int r = t / NCH;
    if (r >= NROI) return;

    RoiMeta m = meta[r];
    const float* f;
    int H;
    switch (m.level) {
        case 0:  f = f0; H = 200; break;
        case 1:  f = f1; H = 100; break;
        case 2:  f = f2; H = 50;  break;
        default: f = f3; H = 25;  break;
    }
    int W = H;
    const float* plane = f + ((size_t)m.bidx * NCH + (size_t)c) * (size_t)H * (size_t)W;

    float acc = 0.0f;
#pragma unroll
    for (int iy = 0; iy < SR; ++iy) {
        float yy = m.y1 + ((float)ph + ((float)iy + 0.5f) * (1.0f / SR)) * m.bin_h;
#pragma unroll
        for (int ix = 0; ix < SR; ++ix) {
            float xx = m.x1 + ((float)pw + ((float)ix + 0.5f) * (1.0f / SR)) * m.bin_w;
            acc += bilinear_legacy(plane, H, W, yy, xx);
        }
    }
    out[idx] = acc * (1.0f / (SR * SR));
}

extern "C" void kernel_launch(void* const* d_in, const int* in_sizes, int n_in,
                              void* d_out, int out_size, void* d_ws, size_t ws_size,
                              hipStream_t stream) {
    const float* f0    = (const float*)d_in[0];
    const float* f1    = (const float*)d_in[1];
    const float* f2    = (const float*)d_in[2];
    const float* f3    = (const float*)d_in[3];
    const float* boxes = (const float*)d_in[4];
    float* out         = (float*)d_out;
    RoiMeta* meta      = (RoiMeta*)d_ws;

    roi_meta_kernel<<<(NROI + 255) / 256, 256, 0, stream>>>(boxes, meta);

    const long long total = (long long)NROI * NCH * OUT * OUT;  // 6,422,528
    const int block = 256;
    const long long grid = (total + block - 1) / block;         // 25,088
    roi_align_kernel<<<(int)grid, block, 0, stream>>>(f0, f1, f2, f3, meta, out);
}

// Round 2
// 203.428 us; speedup vs baseline: 1.0511x; 1.0511x over previous
//
#include <hip/hip_runtime.h>

#define OUT 7
#define NCH 256
#define NB 2
#define NPER 256
#define NROI (NB * NPER)
#define TPR (NCH * OUT * OUT)   // 12544 threads per RoI
#define BPR (TPR / 256)         // 49 blocks per RoI

__device__ __forceinline__ float rfl_f(float v) {
    return __int_as_float(__builtin_amdgcn_readfirstlane(__float_as_int(v)));
}

// One thread per output element. Block swizzle: all 49 blocks of one RoI map
// to the same XCD (blockIdx % 8) and are temporally contiguous there, so a
// RoI's feature working set stays in one 4 MiB L2.
__global__ __launch_bounds__(256) void roi_align_kernel(
        const float* __restrict__ f0, const float* __restrict__ f1,
        const float* __restrict__ f2, const float* __restrict__ f3,
        const float* __restrict__ boxes, float* __restrict__ out) {
    int b    = blockIdx.x;
    int xcd  = b & 7;
    int slot = b >> 3;
    int rr   = slot / BPR;          // 0..63   (RoI group within XCD)
    int j    = slot - rr * BPR;     // 0..48   (block within RoI)
    int r    = (rr << 3) | xcd;     // RoI id; all its blocks share b%8

    int lin = j * 256 + (int)threadIdx.x;   // 0..12543 within RoI
    int pw  = lin % OUT;
    int t   = lin / OUT;
    int ph  = t % OUT;
    int c   = t / OUT;                      // 0..255

    // ---- wave-uniform RoI meta, computed inline (no meta kernel) ----
    float bx1 = rfl_f(boxes[r * 4 + 0]);
    float by1 = rfl_f(boxes[r * 4 + 1]);
    float bx2 = rfl_f(boxes[r * 4 + 2]);
    float by2 = rfl_f(boxes[r * 4 + 3]);

    float area = (bx2 - bx1) * (by2 - by1);
    float s    = sqrtf(area);
    float lvl  = floorf(4.0f + log2f(s * (1.0f / 224.0f) + 1e-6f));
    lvl        = fminf(fmaxf(lvl, 2.0f), 5.0f);
    int level  = __builtin_amdgcn_readfirstlane((int)lvl - 2);

    const float* f;
    int H;
    float scale;
    switch (level) {
        case 0:  f = f0; H = 200; scale = 0.25f;    break;
        case 1:  f = f1; H = 100; scale = 0.125f;   break;
        case 2:  f = f2; H = 50;  scale = 0.0625f;  break;
        default: f = f3; H = 25;  scale = 0.03125f; break;
    }
    float Hf = (float)H;

    float x1 = bx1 * scale;
    float y1 = by1 * scale;
    float roi_w = fmaxf(bx2 * scale - x1, 1.0f);
    float roi_h = fmaxf(by2 * scale - y1, 1.0f);
    float bin_w = roi_w * (1.0f / OUT);
    float bin_h = roi_h * (1.0f / OUT);

    int bidx = r >> 8;   // NPER == 256
    const float* plane = f + (size_t)(bidx * NCH + c) * (size_t)(H * H);

    // ---- phase 1: all 16 tap offsets + weights (validity & 1/4 folded) ----
    float wgt[16];
    int   off[16];
#pragma unroll
    for (int iy = 0; iy < 2; ++iy) {
        float y   = y1 + ((float)ph + (iy ? 0.75f : 0.25f)) * bin_h;
        bool  oky = (y >= -1.0f) && (y <= Hf);
        y = fmaxf(y, 0.0f);
        int yl = (int)y;
        int yh;
        if (yl >= H - 1) { yl = H - 1; yh = H - 1; y = (float)yl; }
        else             { yh = yl + 1; }
        float ly = y - (float)yl;
        float hy = 1.0f - ly;
        int rl = yl * H;
        int rh = yh * H;
#pragma unroll
        for (int ix = 0; ix < 2; ++ix) {
            float x  = x1 + ((float)pw + (ix ? 0.75f : 0.25f)) * bin_w;
            bool  ok = oky && (x >= -1.0f) && (x <= Hf);
            x = fmaxf(x, 0.0f);
            int xl = (int)x;
            int xh;
            if (xl >= H - 1) { xl = H - 1; xh = H - 1; x = (float)xl; }
            else             { xh = xl + 1; }
            float lx = x - (float)xl;
            float hx = 1.0f - lx;
            float m  = ok ? 0.25f : 0.0f;   // fold SR^2 mean + validity
            int k = (iy * 2 + ix) * 4;
            wgt[k + 0] = hy * hx * m;  off[k + 0] = rl + xl;
            wgt[k + 1] = hy * lx * m;  off[k + 1] = rl + xh;
            wgt[k + 2] = ly * hx * m;  off[k + 2] = rh + xl;
            wgt[k + 3] = ly * lx * m;  off[k + 3] = rh + xh;
        }
    }

    // ---- phase 2: 16 independent loads (all in flight) ----
    float v[16];
#pragma unroll
    for (int k = 0; k < 16; ++k) v[k] = plane[off[k]];

    // ---- phase 3: weighted sum ----
    float acc = 0.0f;
#pragma unroll
    for (int k = 0; k < 16; ++k) acc = fmaf(wgt[k], v[k], acc);

    out[(size_t)r * TPR + lin] = acc;
}

extern "C" void kernel_launch(void* const* d_in, const int* in_sizes, int n_in,
                              void* d_out, int out_size, void* d_ws, size_t ws_size,
                              hipStream_t stream) {
    const float* f0    = (const float*)d_in[0];
    const float* f1    = (const float*)d_in[1];
    const float* f2    = (const float*)d_in[2];
    const float* f3    = (const float*)d_in[3];
    const float* boxes = (const float*)d_in[4];
    float* out         = (float*)d_out;

    const int grid = NROI * BPR;   // 25088 blocks, 256 threads each
    roi_align_kernel<<<grid, 256, 0, stream>>>(f0, f1, f2, f3, boxes, out);
}